// Round 1
// baseline (64.370 us; speedup 1.0000x reference)
//
#include <hip/hip_runtime.h>
#include <math.h>

#define S_LEN 512
#define D_DIM 64

typedef __attribute__((ext_vector_type(8))) short bf16x8;
typedef __attribute__((ext_vector_type(4))) float f32x4;

__device__ __forceinline__ short f2bf(float f) {
    // valid for values exactly representable in bf16 (all our cases)
    return (short)(__float_as_uint(f) >> 16);
}
__device__ __forceinline__ float pow2i(int e) {  // 2^e, e in normal range
    return __int_as_float((e + 127) << 23);
}

extern "C" __global__ void __launch_bounds__(512, 2)
mxattn(const float* __restrict__ gmq, const int* __restrict__ geq,
       const float* __restrict__ gmk, const int* __restrict__ gek,
       const float* __restrict__ gmv, const int* __restrict__ gev,
       float* __restrict__ gout)
{
    __shared__ __attribute__((aligned(16))) short Ksw[S_LEN * D_DIM];   // 64 KB, [t][d] swizzled
    __shared__ __attribute__((aligned(16))) short Vsw[D_DIM * S_LEN];   // 64 KB, [d][t] swizzled (transposed)
    __shared__ __attribute__((aligned(16))) float sks[S_LEN];           // 2^(ek-7)
    __shared__ __attribute__((aligned(16))) float sqs[S_LEN];           // 2^(eq-7)
    __shared__ __attribute__((aligned(16))) float tabs[256];            // exp(-k)
    __shared__ __attribute__((aligned(16))) short Psw[8 * 16 * 64];     // 16 KB, per-wave P chunk

    const int b    = blockIdx.x;
    const int tid  = threadIdx.x;
    const int lane = tid & 63;
    const int wave = tid >> 6;
    const int l15  = lane & 15;
    const int lg   = lane >> 4;

    const float* mqb = gmq + (size_t)b * (S_LEN * D_DIM);
    const float* mkb = gmk + (size_t)b * (S_LEN * D_DIM);
    const float* mvb = gmv + (size_t)b * (S_LEN * D_DIM);
    const int* eqb = geq + b * S_LEN;
    const int* ekb = gek + b * S_LEN;
    const int* evb = gev + b * S_LEN;

    // ---------------- staging ----------------
    sqs[tid] = pow2i(eqb[tid] - 7);
    sks[tid] = pow2i(ekb[tid] - 7);
    if (tid < 256) tabs[tid] = (float)exp(-(double)tid);

    char* kbase = (char*)Ksw;
    char* vbase = (char*)Vsw;
    #pragma unroll 4
    for (int i = 0; i < 64; ++i) {
        int t = i * 8 + wave;   // each wave stages full rows; lanes = d
        int d = lane;
        float kv = mkb[t * 64 + d];                       // raw integer mantissa (exact in bf16)
        *(short*)(kbase + t * 128 + ((2 * d) ^ ((t & 7) << 4))) = f2bf(kv);
        float vv = mvb[t * 64 + d] * pow2i(evb[t] - 7);   // dequantized V (exact in bf16)
        *(short*)(vbase + d * 1024 + ((2 * t) ^ ((d & 7) << 4))) = f2bf(vv);
    }
    __syncthreads();

    // 4 passes x (8 waves x 16 rows) = 512 rows
    for (int pass = 0; pass < 4; ++pass) {
        const int r0 = pass * 128 + wave * 16;

        // ---- Q fragments (A-frag: row = l15, k = lg*8+j), raw integer mantissas ----
        bf16x8 qa[2];
        {
            const float* qp = mqb + (size_t)(r0 + l15) * 64 + lg * 8;
            #pragma unroll
            for (int ks = 0; ks < 2; ++ks) {
                f32x4 q0 = *(const f32x4*)(qp + ks * 32);
                f32x4 q1 = *(const f32x4*)(qp + ks * 32 + 4);
                bf16x8 qv;
                qv[0] = f2bf(q0[0]); qv[1] = f2bf(q0[1]);
                qv[2] = f2bf(q0[2]); qv[3] = f2bf(q0[3]);
                qv[4] = f2bf(q1[0]); qv[5] = f2bf(q1[1]);
                qv[6] = f2bf(q1[2]); qv[7] = f2bf(q1[3]);
                qa[ks] = qv;
            }
        }

        // ---- QK^T: exact integer dot products in fp32 accumulators ----
        f32x4 acc[32];
        #pragma unroll
        for (int tt = 0; tt < 32; ++tt) acc[tt] = f32x4{0.f, 0.f, 0.f, 0.f};
        #pragma unroll
        for (int tt = 0; tt < 32; ++tt) {
            int t = tt * 16 + l15;          // B-frag: col(=t) = l15, k(=d) = lg*8+j
            int sw = (t & 7) << 4;
            bf16x8 kf0 = *(const bf16x8*)(kbase + t * 128 + ((16 * lg) ^ sw));
            bf16x8 kf1 = *(const bf16x8*)(kbase + t * 128 + ((64 + 16 * lg) ^ sw));
            acc[tt] = __builtin_amdgcn_mfma_f32_16x16x32_bf16(qa[0], kf0, acc[tt], 0, 0, 0);
            acc[tt] = __builtin_amdgcn_mfma_f32_16x16x32_bf16(qa[1], kf1, acc[tt], 0, 0, 0);
        }

        // ---- scores = int * 2^(eq+ek-14)  (exact), row amax ----
        float sq4[4];
        #pragma unroll
        for (int j = 0; j < 4; ++j) sq4[j] = sqs[r0 + lg * 4 + j];
        float amax4[4] = {0.f, 0.f, 0.f, 0.f};
        #pragma unroll
        for (int tt = 0; tt < 32; ++tt) {
            float skc = sks[tt * 16 + l15];
            #pragma unroll
            for (int j = 0; j < 4; ++j) {
                float s = acc[tt][j] * (sq4[j] * skc);
                acc[tt][j] = s;
                amax4[j] = fmaxf(amax4[j], fabsf(s));
            }
        }
        #pragma unroll
        for (int j = 0; j < 4; ++j)
            #pragma unroll
            for (int off = 1; off < 16; off <<= 1)
                amax4[j] = fmaxf(amax4[j], __shfl_xor(amax4[j], off));

        // ---- score quant: e_s = clip(floor(log2(max(amax,2^-126))), -8, 7) ----
        float msc4[4];
        #pragma unroll
        for (int j = 0; j < 4; ++j) {
            float a = fmaxf(amax4[j], 1.17549435e-38f);
            int es = (int)((__float_as_uint(a) >> 23) & 0xFFu) - 127;  // exact floor(log2)
            es = es < -8 ? -8 : (es > 7 ? 7 : es);
            msc4[j] = pow2i(7 - es);
        }
        float M4[4] = {-3.0e38f, -3.0e38f, -3.0e38f, -3.0e38f};
        #pragma unroll
        for (int tt = 0; tt < 32; ++tt)
            #pragma unroll
            for (int j = 0; j < 4; ++j) {
                float m = rintf(acc[tt][j] * msc4[j]);   // round half-even, matches jnp.round
                m = fminf(fmaxf(m, -128.f), 127.f);
                acc[tt][j] = m;
                M4[j] = fmaxf(M4[j], m);
            }
        #pragma unroll
        for (int j = 0; j < 4; ++j)
            #pragma unroll
            for (int off = 1; off < 16; off <<= 1)
                M4[j] = fmaxf(M4[j], __shfl_xor(M4[j], off));

        // ---- softmax numerators from exp table; row sum ----
        float sum4[4] = {0.f, 0.f, 0.f, 0.f};
        #pragma unroll
        for (int tt = 0; tt < 32; ++tt)
            #pragma unroll
            for (int j = 0; j < 4; ++j) {
                int idx = (int)(M4[j] - acc[tt][j]);     // 0..255
                float e = tabs[idx];
                acc[tt][j] = e;                          // keep numerator for m_p pass
                sum4[j] += e;
            }
        #pragma unroll
        for (int j = 0; j < 4; ++j)
            #pragma unroll
            for (int off = 1; off < 16; off <<= 1)
                sum4[j] += __shfl_xor(sum4[j], off);

        // ---- prob quant scales: amax_p = 1/sum (max prob), e_p, fused scale ----
        float sp4[4], osc4[4];
        #pragma unroll
        for (int j = 0; j < 4; ++j) {
            float pm = 1.0f / sum4[j];
            pm = fmaxf(pm, 1.17549435e-38f);
            int ep = (int)((__float_as_uint(pm) >> 23) & 0xFFu) - 127;
            ep = ep < -8 ? -8 : (ep > 7 ? 7 : ep);
            sp4[j] = pow2i(7 - ep) / sum4[j];   // m_p = rint(num * sp)
            osc4[j] = pow2i(ep - 7);            // ctx row scale
        }

        // ---- PV: quantize P in 16x64 chunks -> per-wave LDS -> MFMA ----
        f32x4 ctx[4];
        #pragma unroll
        for (int dt = 0; dt < 4; ++dt) ctx[dt] = f32x4{0.f, 0.f, 0.f, 0.f};
        char* pbase = (char*)Psw + wave * 2048;
        #pragma unroll
        for (int c = 0; c < 8; ++c) {
            #pragma unroll
            for (int qq = 0; qq < 4; ++qq) {
                int tt = 4 * c + qq;
                #pragma unroll
                for (int j = 0; j < 4; ++j) {
                    float m = rintf(acc[tt][j] * sp4[j]);
                    m = fminf(m, 127.f);                 // probs >= 0
                    int row = lg * 4 + j;                // C-layout row within tile
                    int cc = qq * 16 + l15;              // col within 64-chunk
                    *(short*)(pbase + row * 128 + ((2 * cc) ^ ((row & 7) << 4))) = f2bf(m);
                }
            }
            asm volatile("s_waitcnt lgkmcnt(0)" ::: "memory");  // wave-private P: writes -> reads
            #pragma unroll
            for (int ks = 0; ks < 2; ++ks) {
                bf16x8 pf = *(const bf16x8*)(pbase + l15 * 128 + ((64 * ks + 16 * lg) ^ ((l15 & 7) << 4)));
                int tcol = c * 64 + ks * 32 + lg * 8;
                #pragma unroll
                for (int dt = 0; dt < 4; ++dt) {
                    int drow = dt * 16 + l15;
                    bf16x8 vf = *(const bf16x8*)(vbase + drow * 1024 + ((2 * tcol) ^ ((drow & 7) << 4)));
                    ctx[dt] = __builtin_amdgcn_mfma_f32_16x16x32_bf16(pf, vf, ctx[dt], 0, 0, 0);
                }
            }
        }

        // ---- ctx scale, output quant, dequant, store ----
        float a4[4] = {0.f, 0.f, 0.f, 0.f};
        #pragma unroll
        for (int dt = 0; dt < 4; ++dt)
            #pragma unroll
            for (int j = 0; j < 4; ++j) {
                float cval = ctx[dt][j] * osc4[j];
                ctx[dt][j] = cval;
                a4[j] = fmaxf(a4[j], fabsf(cval));
            }
        #pragma unroll
        for (int j = 0; j < 4; ++j)
            #pragma unroll
            for (int off = 1; off < 16; off <<= 1)
                a4[j] = fmaxf(a4[j], __shfl_xor(a4[j], off));
        float csc4[4], oo4[4];
        #pragma unroll
        for (int j = 0; j < 4; ++j) {
            float a = fmaxf(a4[j], 1.17549435e-38f);
            int ec = (int)((__float_as_uint(a) >> 23) & 0xFFu) - 127;
            ec = ec < -8 ? -8 : (ec > 7 ? 7 : ec);
            csc4[j] = pow2i(7 - ec);
            oo4[j] = pow2i(ec - 7);
        }
        #pragma unroll
        for (int dt = 0; dt < 4; ++dt)
            #pragma unroll
            for (int j = 0; j < 4; ++j) {
                float m = rintf(ctx[dt][j] * csc4[j]);
                m = fminf(fmaxf(m, -128.f), 127.f);
                gout[((size_t)b * S_LEN + r0 + lg * 4 + j) * D_DIM + dt * 16 + l15] = m * oo4[j];
            }
    }
}

extern "C" void kernel_launch(void* const* d_in, const int* in_sizes, int n_in,
                              void* d_out, int out_size, void* d_ws, size_t ws_size,
                              hipStream_t stream) {
    const float* mq = (const float*)d_in[0];
    const int*   eq = (const int*)d_in[1];
    const float* mk = (const float*)d_in[2];
    const int*   ek = (const int*)d_in[3];
    const float* mv = (const float*)d_in[4];
    const int*   ev = (const int*)d_in[5];
    float* out = (float*)d_out;
    int B = in_sizes[1] / S_LEN;   // 256
    mxattn<<<B, 512, 0, stream>>>(mq, eq, mk, ek, mv, ev, out);
}